// Round 1
// baseline (1257.773 us; speedup 1.0000x reference)
//
#include <hip/hip_runtime.h>

#define S_LEN 2048
#define D_DIM 256
#define BM 64
#define BN 64

typedef float  float4v __attribute__((ext_vector_type(4)));
typedef short  short8  __attribute__((ext_vector_type(8)));
typedef __bf16 bf16x4  __attribute__((ext_vector_type(4)));
typedef __bf16 bf16x2  __attribute__((ext_vector_type(2)));

// 1/16 (reference SCALE) * log2(e): folds softmax's exp->exp2 conversion into Q.
#define QSCALE (0.0625f * 1.44269504088896340736f)
#define NEG_BIG (-3.0e38f)

__global__ __launch_bounds__(256, 3)
void fa_fwd(const float* __restrict__ Qg, const float* __restrict__ Kg,
            const float* __restrict__ Vg, float* __restrict__ Og)
{
    // union buffer: K tile [64][256+8] bf16 (16896 el)  OR  V^T tile [256][64+8] (18432 el)
    __shared__ __bf16 kv[256 * 72];
    // per-wave P tile [16][64+8] bf16 (C-layout -> A-layout round trip)
    __shared__ __bf16 pbuf[4 * 16 * 72];

    const int tid  = threadIdx.x;
    const int wave = tid >> 6;
    const int lane = tid & 63;
    const int n16  = lane & 15;   // MFMA m/n lane index
    const int quad = lane >> 4;   // MFMA k-group

    // XCD swizzle: blockIdx % 8 ~ XCD id; keep one (b,h) per XCD at a time so its
    // 4MB K/V working set lives in that XCD's 4MB L2.
    const int linear = blockIdx.x;
    const int bh = ((linear & 7) << 2) + (linear >> 8);   // 0..31
    const int qt = (linear >> 3) & 31;                    // 0..31

    const size_t base = (size_t)bh * S_LEN * D_DIM;

    // ---- Q fragments (A-layout: A[m=n16][k=quad*8+j]), once per block ----
    short8 qfrag[8];
    {
        const float* qrow = Qg + base + (size_t)(qt * BM + wave * 16 + n16) * D_DIM;
        #pragma unroll
        for (int kk = 0; kk < 8; ++kk) {
            const float4v a = *(const float4v*)(qrow + kk * 32 + quad * 8);
            const float4v b = *(const float4v*)(qrow + kk * 32 + quad * 8 + 4);
            short8 f;
            f[0] = __builtin_bit_cast(short, (__bf16)(a[0] * QSCALE));
            f[1] = __builtin_bit_cast(short, (__bf16)(a[1] * QSCALE));
            f[2] = __builtin_bit_cast(short, (__bf16)(a[2] * QSCALE));
            f[3] = __builtin_bit_cast(short, (__bf16)(a[3] * QSCALE));
            f[4] = __builtin_bit_cast(short, (__bf16)(b[0] * QSCALE));
            f[5] = __builtin_bit_cast(short, (__bf16)(b[1] * QSCALE));
            f[6] = __builtin_bit_cast(short, (__bf16)(b[2] * QSCALE));
            f[7] = __builtin_bit_cast(short, (__bf16)(b[3] * QSCALE));
            qfrag[kk] = f;
        }
    }

    float4v oacc[16];
    #pragma unroll
    for (int i = 0; i < 16; ++i) oacc[i] = (float4v){0.f, 0.f, 0.f, 0.f};
    float m_run[4] = {NEG_BIG, NEG_BIG, NEG_BIG, NEG_BIG};
    float l_run[4] = {0.f, 0.f, 0.f, 0.f};

    for (int kt = 0; kt < S_LEN / BN; ++kt) {
        // ---- stage K tile: fp32 global -> bf16 LDS [64][264] ----
        {
            const float* kbase = Kg + base + (size_t)kt * BN * D_DIM;
            #pragma unroll 4
            for (int it = 0; it < 16; ++it) {
                const int g   = it * 256 + tid;
                const int row = g >> 6;          // key row 0..63
                const int dc  = (g & 63) << 2;   // d offset, step 4
                const float4v v = *(const float4v*)(kbase + row * D_DIM + dc);
                bf16x4 w;
                w[0] = (__bf16)v[0]; w[1] = (__bf16)v[1];
                w[2] = (__bf16)v[2]; w[3] = (__bf16)v[3];
                *(bf16x4*)&kv[row * 264 + dc] = w;
            }
        }
        __syncthreads();

        // ---- S = Q K^T (pre-scaled) ----
        float4v sacc[4];
        #pragma unroll
        for (int nt = 0; nt < 4; ++nt) {
            float4v acc = {0.f, 0.f, 0.f, 0.f};
            const __bf16* kp = &kv[(nt * 16 + n16) * 264 + quad * 8];
            #pragma unroll
            for (int kk = 0; kk < 8; ++kk) {
                const short8 bfr = *(const short8*)(kp + kk * 32);
                acc = __builtin_amdgcn_mfma_f32_16x16x32_bf16(qfrag[kk], bfr, acc, 0, 0, 0);
            }
            sacc[nt] = acc;
        }
        __syncthreads();   // all waves done reading K before V overwrites the buffer

        // ---- stage V tile transposed: fp32 [64][256] -> bf16 LDS V^T [256][72] ----
        {
            const float* vbase = Vg + base + (size_t)kt * BN * D_DIM;
            #pragma unroll 4
            for (int it = 0; it < 8; ++it) {
                const int tsk = it * 256 + tid;
                const int kp2 = tsk >> 6;          // key pair 0..31
                const int dc  = (tsk & 63) << 2;   // d chunk
                const float4v v0 = *(const float4v*)(vbase + (2 * kp2    ) * D_DIM + dc);
                const float4v v1 = *(const float4v*)(vbase + (2 * kp2 + 1) * D_DIM + dc);
                #pragma unroll
                for (int i = 0; i < 4; ++i) {
                    bf16x2 w; w[0] = (__bf16)v0[i]; w[1] = (__bf16)v1[i];
                    *(bf16x2*)&kv[(dc + i) * 72 + 2 * kp2] = w;
                }
            }
        }

        // ---- online softmax (per wave; rows = quad*4+r in C-layout) ----
        #pragma unroll
        for (int r = 0; r < 4; ++r) {
            float mx = fmaxf(fmaxf(sacc[0][r], sacc[1][r]), fmaxf(sacc[2][r], sacc[3][r]));
            mx = fmaxf(mx, __shfl_xor(mx, 1));
            mx = fmaxf(mx, __shfl_xor(mx, 2));
            mx = fmaxf(mx, __shfl_xor(mx, 4));
            mx = fmaxf(mx, __shfl_xor(mx, 8));
            const float mn = fmaxf(m_run[r], mx);
            const float al = exp2f(m_run[r] - mn);
            m_run[r] = mn;
            float ps = 0.f;
            __bf16* prow = &pbuf[wave * 1152 + (quad * 4 + r) * 72 + n16];
            #pragma unroll
            for (int nt = 0; nt < 4; ++nt) {
                const float p = exp2f(sacc[nt][r] - mn);
                ps += p;
                prow[nt * 16] = (__bf16)p;
            }
            ps += __shfl_xor(ps, 1);
            ps += __shfl_xor(ps, 2);
            ps += __shfl_xor(ps, 4);
            ps += __shfl_xor(ps, 8);
            l_run[r] = l_run[r] * al + ps;
            #pragma unroll
            for (int dt = 0; dt < 16; ++dt) oacc[dt][r] *= al;
        }
        __syncthreads();   // V^T staged (and covers P write->read lgkm ordering)

        // ---- O += P V ----
        #pragma unroll
        for (int kth = 0; kth < 2; ++kth) {
            const short8 af = *(const short8*)&pbuf[wave * 1152 + n16 * 72 + kth * 32 + quad * 8];
            #pragma unroll
            for (int dt = 0; dt < 16; ++dt) {
                const short8 bfr = *(const short8*)&kv[(dt * 16 + n16) * 72 + kth * 32 + quad * 8];
                oacc[dt] = __builtin_amdgcn_mfma_f32_16x16x32_bf16(af, bfr, oacc[dt], 0, 0, 0);
            }
        }
        __syncthreads();   // done with V^T before next iteration stages K
    }

    // ---- epilogue: O / l, store fp32 [B,H,S,D] ----
    float* obase = Og + base + (size_t)(qt * BM + wave * 16) * D_DIM;
    #pragma unroll
    for (int r = 0; r < 4; ++r) {
        const float inv = 1.0f / l_run[r];
        const int row = quad * 4 + r;
        #pragma unroll
        for (int dt = 0; dt < 16; ++dt) {
            obase[row * D_DIM + dt * 16 + n16] = oacc[dt][r] * inv;
        }
    }
}

extern "C" void kernel_launch(void* const* d_in, const int* in_sizes, int n_in,
                              void* d_out, int out_size, void* d_ws, size_t ws_size,
                              hipStream_t stream) {
    const float* Q = (const float*)d_in[0];
    const float* K = (const float*)d_in[1];
    const float* V = (const float*)d_in[2];
    float* O = (float*)d_out;
    (void)in_sizes; (void)n_in; (void)out_size; (void)d_ws; (void)ws_size;
    fa_fwd<<<dim3((S_LEN / BM) * 32), dim3(256), 0, stream>>>(Q, K, V, O);
}

// Round 2
// 436.869 us; speedup vs baseline: 2.8791x; 2.8791x over previous
//
#include <hip/hip_runtime.h>

#define S_LEN 2048
#define D_DIM 256
#define NBH   32
#define BM    64
#define BN    64
#define NKT   32
#define TILE_ELS 16384   /* 64x256 bf16 elements per image tile (32 KB) */
#define WS_NEED  67108864ull

typedef float    float4v __attribute__((ext_vector_type(4)));
typedef short    short8  __attribute__((ext_vector_type(8)));
typedef unsigned uint4v  __attribute__((ext_vector_type(4)));
typedef __bf16   bf16x8  __attribute__((ext_vector_type(8)));
typedef __bf16   bf16x2  __attribute__((ext_vector_type(2)));
typedef __bf16   bf16x4  __attribute__((ext_vector_type(4)));

#define QSCALE (0.0625f * 1.44269504088896340736f)
#define NEG_BIG (-3.0e38f)

typedef __attribute__((address_space(1))) const void gv_t;
typedef __attribute__((address_space(3))) void lv_t;

// ---------------- prepass 1: K fp32 -> swizzled bf16 tile images ----------------
// image tile (bh,kt): element (s,d) at byte  s*512 + ((d>>3 ^ (s&7))*16) + (d&7)*2
__global__ __launch_bounds__(256) void prep_k(const float* __restrict__ Kg,
                                              __bf16* __restrict__ kimg) {
    const int gi = blockIdx.x * 256 + threadIdx.x;   // one 16B chunk each
    const int c  = gi & 31;           // d-chunk 0..31
    const int sg = gi >> 5;           // bh*2048 + s
    const int s  = sg & 2047;
    const int kt = s >> 6;
    const int sr = s & 63;
    const int bh = sg >> 11;
    const float* src = Kg + ((size_t)sg << 8) + (c << 3);
    const float4v a = *(const float4v*)src;
    const float4v b = *(const float4v*)(src + 4);
    bf16x8 w;
    w[0]=(__bf16)a[0]; w[1]=(__bf16)a[1]; w[2]=(__bf16)a[2]; w[3]=(__bf16)a[3];
    w[4]=(__bf16)b[0]; w[5]=(__bf16)b[1]; w[6]=(__bf16)b[2]; w[7]=(__bf16)b[3];
    const int cp = c ^ (sr & 7);
    *(bf16x8*)(kimg + ((size_t)(bh * NKT + kt) << 14) + sr * 256 + cp * 8) = w;
}

// ---------------- prepass 2: V fp32 -> transposed swizzled bf16 images ----------
// image tile (bh,kt): element (d, s) at byte  d*128 + ((s>>3 ^ (d&7))*16) + (s&7)*2
__global__ __launch_bounds__(256) void prep_v(const float* __restrict__ Vg,
                                              __bf16* __restrict__ vimg) {
    __shared__ __bf16 t[64 * 258];
    const int tid = threadIdx.x;
    const int blk = blockIdx.x;                       // bh*32 + kt
    const float* src = Vg + ((size_t)blk << 14);
    #pragma unroll 4
    for (int i = 0; i < 16; ++i) {
        const int g = i * 256 + tid;
        const int s = g >> 6;
        const int d = (g & 63) << 2;
        const float4v v = *(const float4v*)(src + s * 256 + d);
        __bf16* p = &t[s * 258 + d];
        *(bf16x2*)p       = (bf16x2){(__bf16)v[0], (__bf16)v[1]};
        *(bf16x2*)(p + 2) = (bf16x2){(__bf16)v[2], (__bf16)v[3]};
    }
    __syncthreads();
    __bf16* dst = vimg + ((size_t)blk << 14);
    #pragma unroll 2
    for (int i = 0; i < 8; ++i) {
        const int d = i * 32 + (tid >> 3);
        const int c = tid & 7;
        bf16x8 w;
        #pragma unroll
        for (int k = 0; k < 8; ++k) w[k] = t[(c * 8 + k) * 258 + d];
        const int cp = c ^ (d & 7);
        *(bf16x8*)(dst + d * 64 + cp * 8) = w;
    }
}

// ---------------- main flash kernel --------------------------------------------
__device__ __forceinline__ void dma8(const char* g, char* l) {
    #pragma unroll
    for (int i = 0; i < 8; ++i)
        __builtin_amdgcn_global_load_lds((gv_t*)(g + i * 1024), (lv_t*)(l + i * 1024), 16, 0, 0);
}

__device__ __forceinline__ int pack_bf16(float a, float b) {
    const unsigned short ua = __builtin_bit_cast(unsigned short, (__bf16)a);
    const unsigned short ub = __builtin_bit_cast(unsigned short, (__bf16)b);
    return (int)((unsigned)ua | ((unsigned)ub << 16));
}

__global__ __launch_bounds__(256, 2)
void fa_main(const float* __restrict__ Qg, const __bf16* __restrict__ kimg,
             const __bf16* __restrict__ vimg, float* __restrict__ Og) {
    __shared__ __bf16 Kbuf[64 * 256];   // 32 KB swizzled K image
    __shared__ __bf16 Vbuf[256 * 64];   // 32 KB swizzled V^T image

    const int tid  = threadIdx.x;
    const int wave = tid >> 6;
    const int lane = tid & 63;
    const int n16  = lane & 15;
    const int quad = lane >> 4;
    const int n167 = n16 & 7;

    const int linear = blockIdx.x;
    const int bh = ((linear & 7) << 2) + (linear >> 8);
    const int qt = (linear >> 3) & 31;

    const size_t base = (size_t)bh * (S_LEN * D_DIM);
    const char* ktile = (const char*)(kimg + ((size_t)bh << 19));  // bh * 32*16384 els
    const char* vtile = (const char*)(vimg + ((size_t)bh << 19));
    const int woff = wave * 8192 + lane * 16;   // per-lane DMA source offset within tile
    char* kl = (char*)Kbuf + wave * 8192;       // wave-uniform LDS dest
    char* vl = (char*)Vbuf + wave * 8192;

    // ---- Q fragments (B operand: B[k=quad*8+j][n=query n16]) ----
    short8 qfrag[8];
    {
        const float* qrow = Qg + base + (size_t)(qt * BM + wave * 16 + n16) * D_DIM;
        #pragma unroll
        for (int kk = 0; kk < 8; ++kk) {
            const float4v a = *(const float4v*)(qrow + kk * 32 + quad * 8);
            const float4v b = *(const float4v*)(qrow + kk * 32 + quad * 8 + 4);
            short8 f;
            f[0] = __builtin_bit_cast(short, (__bf16)(a[0] * QSCALE));
            f[1] = __builtin_bit_cast(short, (__bf16)(a[1] * QSCALE));
            f[2] = __builtin_bit_cast(short, (__bf16)(a[2] * QSCALE));
            f[3] = __builtin_bit_cast(short, (__bf16)(a[3] * QSCALE));
            f[4] = __builtin_bit_cast(short, (__bf16)(b[0] * QSCALE));
            f[5] = __builtin_bit_cast(short, (__bf16)(b[1] * QSCALE));
            f[6] = __builtin_bit_cast(short, (__bf16)(b[2] * QSCALE));
            f[7] = __builtin_bit_cast(short, (__bf16)(b[3] * QSCALE));
            qfrag[kk] = f;
        }
    }

    float4v oacc[16];
    #pragma unroll
    for (int i = 0; i < 16; ++i) oacc[i] = (float4v){0.f, 0.f, 0.f, 0.f};
    float m_run = NEG_BIG, l_run = 0.f;   // per-lane: softmax state of query n16

    // preload tile 0 (K and V)
    dma8(ktile + woff, kl);
    dma8(vtile + woff, vl);

    const int srcA = n16 + ((lane & 16) << 1);   // lane(n16, quad'=2*(q&1))
    const int srcB = srcA + 16;                  // lane(n16, quad'=2*(q&1)+1)
    const bool hi  = (quad >> 1) != 0;           // readers q>=2 take nt=2*kth+1

    for (int kt = 0; kt < NKT; ++kt) {
        __syncthreads();   // drains K(kt) [+V(0) first iter]; all waves done with kt-1 bufs
        if (kt > 0) dma8(vtile + kt * 32768 + woff, vl);   // V(kt): lands before barrier B

        // ---- S^T = K * Q^T : lane holds keys {16nt+4quad+r}, query n16 ----
        float4v sacc[4];
        #pragma unroll
        for (int nt = 0; nt < 4; ++nt) {
            float4v acc = {0.f, 0.f, 0.f, 0.f};
            const __bf16* kp = &Kbuf[(nt * 16 + n16) * 256];
            #pragma unroll
            for (int kk = 0; kk < 8; ++kk) {
                const short8 kfrag = *(const short8*)(kp + (((4 * kk + quad) ^ n167) << 3));
                acc = __builtin_amdgcn_mfma_f32_16x16x32_bf16(kfrag, qfrag[kk], acc, 0, 0, 0);
            }
            sacc[nt] = acc;
        }

        // ---- online softmax: lane-local over 16 keys, cross-quad over 64 ----
        float mx = sacc[0][0];
        #pragma unroll
        for (int nt = 0; nt < 4; ++nt)
            #pragma unroll
            for (int r = 0; r < 4; ++r) mx = fmaxf(mx, sacc[nt][r]);
        mx = fmaxf(mx, __shfl_xor(mx, 16));
        mx = fmaxf(mx, __shfl_xor(mx, 32));
        const float mn = fmaxf(m_run, mx);
        const float al = exp2f(m_run - mn);
        m_run = mn;

        float ps = 0.f;
        int pk[4][2];
        #pragma unroll
        for (int nt = 0; nt < 4; ++nt) {
            float p0 = exp2f(sacc[nt][0] - mn);
            float p1 = exp2f(sacc[nt][1] - mn);
            float p2 = exp2f(sacc[nt][2] - mn);
            float p3 = exp2f(sacc[nt][3] - mn);
            ps += (p0 + p1) + (p2 + p3);
            pk[nt][0] = pack_bf16(p0, p1);
            pk[nt][1] = pack_bf16(p2, p3);
        }
        ps += __shfl_xor(ps, 16);
        ps += __shfl_xor(ps, 32);
        l_run = l_run * al + ps;

        // rescale O (rows are queries 4*quad+r; alpha lives at lane n16=4*quad+r)
        #pragma unroll
        for (int r = 0; r < 4; ++r) {
            const float alr = __shfl(al, (quad << 4) + (quad << 2) + r);
            #pragma unroll
            for (int dt = 0; dt < 16; ++dt) oacc[dt][r] *= alr;
        }

        __syncthreads();   // drains V(kt); Kbuf free
        if (kt < NKT - 1) dma8(ktile + (kt + 1) * 32768 + woff, kl);  // overlaps PV

        // ---- P: C-layout -> A-frags via cross-quad shuffles ----
        short8 pfrag[2];
        #pragma unroll
        for (int kth = 0; kth < 2; ++kth) {
            const int a0 = __shfl(pk[2 * kth][0], srcA), a1 = __shfl(pk[2 * kth + 1][0], srcA);
            const int b0 = __shfl(pk[2 * kth][1], srcA), b1 = __shfl(pk[2 * kth + 1][1], srcA);
            const int c0 = __shfl(pk[2 * kth][0], srcB), c1 = __shfl(pk[2 * kth + 1][0], srcB);
            const int d0 = __shfl(pk[2 * kth][1], srcB), d1 = __shfl(pk[2 * kth + 1][1], srcB);
            uint4v u;
            u[0] = (unsigned)(hi ? a1 : a0);
            u[1] = (unsigned)(hi ? b1 : b0);
            u[2] = (unsigned)(hi ? c1 : c0);
            u[3] = (unsigned)(hi ? d1 : d0);
            pfrag[kth] = __builtin_bit_cast(short8, u);
        }

        // ---- O += P V  (B-frags from swizzled V^T image) ----
        #pragma unroll
        for (int kth = 0; kth < 2; ++kth) {
            #pragma unroll
            for (int dt = 0; dt < 16; ++dt) {
                const short8 vfrag = *(const short8*)
                    &Vbuf[(dt * 16 + n16) * 64 + (((4 * kth + quad) ^ n167) << 3)];
                oacc[dt] = __builtin_amdgcn_mfma_f32_16x16x32_bf16(pfrag[kth], vfrag, oacc[dt], 0, 0, 0);
            }
        }
    }

    // ---- epilogue ----
    float* obase = Og + base + (size_t)(qt * BM + wave * 16) * D_DIM;
    #pragma unroll
    for (int r = 0; r < 4; ++r) {
        const float lr  = __shfl(l_run, (quad << 4) + (quad << 2) + r);
        const float inv = 1.0f / lr;
        const int row = (quad << 2) + r;
        #pragma unroll
        for (int dt = 0; dt < 16; ++dt)
            obase[row * D_DIM + dt * 16 + n16] = oacc[dt][r] * inv;
    }
}

// ---------------- fallback (round-1 kernel, used when ws too small) -------------
__global__ __launch_bounds__(256, 3)
void fa_fallback(const float* __restrict__ Qg, const float* __restrict__ Kg,
                 const float* __restrict__ Vg, float* __restrict__ Og)
{
    __shared__ __bf16 kv[256 * 72];
    __shared__ __bf16 pbuf[4 * 16 * 72];
    const int tid = threadIdx.x, wave = tid >> 6, lane = tid & 63;
    const int n16 = lane & 15, quad = lane >> 4;
    const int linear = blockIdx.x;
    const int bh = ((linear & 7) << 2) + (linear >> 8);
    const int qt = (linear >> 3) & 31;
    const size_t base = (size_t)bh * S_LEN * D_DIM;
    short8 qfrag[8];
    {
        const float* qrow = Qg + base + (size_t)(qt * BM + wave * 16 + n16) * D_DIM;
        #pragma unroll
        for (int kk = 0; kk < 8; ++kk) {
            const float4v a = *(const float4v*)(qrow + kk * 32 + quad * 8);
            const float4v b = *(const float4v*)(qrow + kk * 32 + quad * 8 + 4);
            short8 f;
            f[0] = __builtin_bit_cast(short, (__bf16)(a[0] * QSCALE));
            f[1] = __builtin_bit_cast(short, (__bf16)(a[1] * QSCALE));
            f[2] = __builtin_bit_cast(short, (__bf16)(a[2] * QSCALE));
            f[3] = __builtin_bit_cast(short, (__bf16)(a[3] * QSCALE));
            f[4] = __builtin_bit_cast(short, (__bf16)(b[0] * QSCALE));
            f[5] = __builtin_bit_cast(short, (__bf16)(b[1] * QSCALE));
            f[6] = __builtin_bit_cast(short, (__bf16)(b[2] * QSCALE));
            f[7] = __builtin_bit_cast(short, (__bf16)(b[3] * QSCALE));
            qfrag[kk] = f;
        }
    }
    float4v oacc[16];
    #pragma unroll
    for (int i = 0; i < 16; ++i) oacc[i] = (float4v){0.f, 0.f, 0.f, 0.f};
    float m_run[4] = {NEG_BIG, NEG_BIG, NEG_BIG, NEG_BIG};
    float l_run[4] = {0.f, 0.f, 0.f, 0.f};
    for (int kt = 0; kt < S_LEN / BN; ++kt) {
        {
            const float* kbase = Kg + base + (size_t)kt * BN * D_DIM;
            #pragma unroll 4
            for (int it = 0; it < 16; ++it) {
                const int g = it * 256 + tid;
                const int row = g >> 6;
                const int dc = (g & 63) << 2;
                const float4v v = *(const float4v*)(kbase + row * D_DIM + dc);
                bf16x4 w;
                w[0] = (__bf16)v[0]; w[1] = (__bf16)v[1];
                w[2] = (__bf16)v[2]; w[3] = (__bf16)v[3];
                *(bf16x4*)&kv[row * 264 + dc] = w;
            }
        }
        __syncthreads();
        float4v sacc[4];
        #pragma unroll
        for (int nt = 0; nt < 4; ++nt) {
            float4v acc = {0.f, 0.f, 0.f, 0.f};
            const __bf16* kp = &kv[(nt * 16 + n16) * 264 + quad * 8];
            #pragma unroll
            for (int kk = 0; kk < 8; ++kk) {
                const short8 bfr = *(const short8*)(kp + kk * 32);
                acc = __builtin_amdgcn_mfma_f32_16x16x32_bf16(qfrag[kk], bfr, acc, 0, 0, 0);
            }
            sacc[nt] = acc;
        }
        __syncthreads();
        {
            const float* vbase = Vg + base + (size_t)kt * BN * D_DIM;
            #pragma unroll 4
            for (int it = 0; it < 8; ++it) {
                const int tsk = it * 256 + tid;
                const int kp2 = tsk >> 6;
                const int dc = (tsk & 63) << 2;
                const float4v v0 = *(const float4v*)(vbase + (2 * kp2) * D_DIM + dc);
                const float4v v1 = *(const float4v*)(vbase + (2 * kp2 + 1) * D_DIM + dc);
                #pragma unroll
                for (int i = 0; i < 4; ++i) {
                    bf16x2 w; w[0] = (__bf16)v0[i]; w[1] = (__bf16)v1[i];
                    *(bf16x2*)&kv[(dc + i) * 72 + 2 * kp2] = w;
                }
            }
        }
        #pragma unroll
        for (int r = 0; r < 4; ++r) {
            float mx = fmaxf(fmaxf(sacc[0][r], sacc[1][r]), fmaxf(sacc[2][r], sacc[3][r]));
            mx = fmaxf(mx, __shfl_xor(mx, 1));
            mx = fmaxf(mx, __shfl_xor(mx, 2));
            mx = fmaxf(mx, __shfl_xor(mx, 4));
            mx = fmaxf(mx, __shfl_xor(mx, 8));
            const float mn = fmaxf(m_run[r], mx);
            const float al = exp2f(m_run[r] - mn);
            m_run[r] = mn;
            float ps = 0.f;
            __bf16* prow = &pbuf[wave * 1152 + (quad * 4 + r) * 72 + n16];
            #pragma unroll
            for (int nt = 0; nt < 4; ++nt) {
                const float p = exp2f(sacc[nt][r] - mn);
                ps += p;
                prow[nt * 16] = (__bf16)p;
            }
            ps += __shfl_xor(ps, 1);
            ps += __shfl_xor(ps, 2);
            ps += __shfl_xor(ps, 4);
            ps += __shfl_xor(ps, 8);
            l_run[r] = l_run[r] * al + ps;
            #pragma unroll
            for (int dt = 0; dt < 16; ++dt) oacc[dt][r] *= al;
        }
        __syncthreads();
        #pragma unroll
        for (int kth = 0; kth < 2; ++kth) {
            const short8 af = *(const short8*)&pbuf[wave * 1152 + n16 * 72 + kth * 32 + quad * 8];
            #pragma unroll
            for (int dt = 0; dt < 16; ++dt) {
                const short8 bfr = *(const short8*)&kv[(dt * 16 + n16) * 72 + kth * 32 + quad * 8];
                oacc[dt] = __builtin_amdgcn_mfma_f32_16x16x32_bf16(af, bfr, oacc[dt], 0, 0, 0);
            }
        }
        __syncthreads();
    }
    float* obase = Og + base + (size_t)(qt * BM + wave * 16) * D_DIM;
    #pragma unroll
    for (int r = 0; r < 4; ++r) {
        const float inv = 1.0f / l_run[r];
        const int row = quad * 4 + r;
        #pragma unroll
        for (int dt = 0; dt < 16; ++dt)
            obase[row * D_DIM + dt * 16 + n16] = oacc[dt][r] * inv;
    }
}

extern "C" void kernel_launch(void* const* d_in, const int* in_sizes, int n_in,
                              void* d_out, int out_size, void* d_ws, size_t ws_size,
                              hipStream_t stream) {
    const float* Q = (const float*)d_in[0];
    const float* K = (const float*)d_in[1];
    const float* V = (const float*)d_in[2];
    float* O = (float*)d_out;
    (void)in_sizes; (void)n_in; (void)out_size;
    if (ws_size >= WS_NEED) {
        __bf16* kimg = (__bf16*)d_ws;
        __bf16* vimg = kimg + (size_t)NBH * NKT * TILE_ELS;
        prep_k<<<dim3(8192), dim3(256), 0, stream>>>(K, kimg);
        prep_v<<<dim3(1024), dim3(256), 0, stream>>>(V, vimg);
        fa_main<<<dim3(1024), dim3(256), 0, stream>>>(Q, kimg, vimg, O);
    } else {
        fa_fallback<<<dim3(1024), dim3(256), 0, stream>>>(Q, K, V, O);
    }
}

// Round 3
// 436.132 us; speedup vs baseline: 2.8839x; 1.0017x over previous
//
#include <hip/hip_runtime.h>

#define S_LEN 2048
#define D_DIM 256
#define NBH   32
#define BM    128
#define BN    64
#define NKT   32
#define TILE_ELS 16384   /* 64x256 bf16 elements per image tile (32 KB) */
#define WS_NEED  67108864ull

typedef float    float4v __attribute__((ext_vector_type(4)));
typedef short    short8  __attribute__((ext_vector_type(8)));
typedef unsigned uint4v  __attribute__((ext_vector_type(4)));
typedef __bf16   bf16x8  __attribute__((ext_vector_type(8)));
typedef __bf16   bf16x2  __attribute__((ext_vector_type(2)));
typedef __bf16   bf16x4  __attribute__((ext_vector_type(4)));

#define QSCALE (0.0625f * 1.44269504088896340736f)
#define NEG_BIG (-3.0e38f)

typedef __attribute__((address_space(1))) const void gv_t;
typedef __attribute__((address_space(3))) void lv_t;

// ---------------- prepass 1: K fp32 -> swizzled bf16 tile images ----------------
// image tile (bh,kt): element (s,d) at byte  s*512 + ((d>>3 ^ (s&7))*16) + (d&7)*2
__global__ __launch_bounds__(256) void prep_k(const float* __restrict__ Kg,
                                              __bf16* __restrict__ kimg) {
    const int gi = blockIdx.x * 256 + threadIdx.x;   // one 16B chunk each
    const int c  = gi & 31;           // d-chunk 0..31
    const int sg = gi >> 5;           // bh*2048 + s
    const int s  = sg & 2047;
    const int kt = s >> 6;
    const int sr = s & 63;
    const int bh = sg >> 11;
    const float* src = Kg + ((size_t)sg << 8) + (c << 3);
    const float4v a = *(const float4v*)src;
    const float4v b = *(const float4v*)(src + 4);
    bf16x8 w;
    w[0]=(__bf16)a[0]; w[1]=(__bf16)a[1]; w[2]=(__bf16)a[2]; w[3]=(__bf16)a[3];
    w[4]=(__bf16)b[0]; w[5]=(__bf16)b[1]; w[6]=(__bf16)b[2]; w[7]=(__bf16)b[3];
    const int cp = c ^ (sr & 7);
    *(bf16x8*)(kimg + ((size_t)(bh * NKT + kt) << 14) + sr * 256 + cp * 8) = w;
}

// ---------------- prepass 2: V fp32 -> transposed swizzled bf16 images ----------
// image tile (bh,kt): element (d, s) at byte  d*128 + ((s>>3 ^ (d&7))*16) + (s&7)*2
__global__ __launch_bounds__(256) void prep_v(const float* __restrict__ Vg,
                                              __bf16* __restrict__ vimg) {
    __shared__ __bf16 t[64 * 258];
    const int tid = threadIdx.x;
    const int blk = blockIdx.x;                       // bh*32 + kt
    const float* src = Vg + ((size_t)blk << 14);
    #pragma unroll 4
    for (int i = 0; i < 16; ++i) {
        const int g = i * 256 + tid;
        const int s = g >> 6;
        const int d = (g & 63) << 2;
        const float4v v = *(const float4v*)(src + s * 256 + d);
        __bf16* p = &t[s * 258 + d];
        *(bf16x2*)p       = (bf16x2){(__bf16)v[0], (__bf16)v[1]};
        *(bf16x2*)(p + 2) = (bf16x2){(__bf16)v[2], (__bf16)v[3]};
    }
    __syncthreads();
    __bf16* dst = vimg + ((size_t)blk << 14);
    #pragma unroll 2
    for (int i = 0; i < 8; ++i) {
        const int d = i * 32 + (tid >> 3);
        const int c = tid & 7;
        bf16x8 w;
        #pragma unroll
        for (int k = 0; k < 8; ++k) w[k] = t[(c * 8 + k) * 258 + d];
        const int cp = c ^ (d & 7);
        *(bf16x8*)(dst + d * 64 + cp * 8) = w;
    }
}

// ---------------- main flash kernel --------------------------------------------
// per-wave DMA: 4 KB slice (4 x 1 KB x 16B/lane)
__device__ __forceinline__ void dma4(const char* g, char* l) {
    #pragma unroll
    for (int i = 0; i < 4; ++i)
        __builtin_amdgcn_global_load_lds((gv_t*)(g + i * 1024), (lv_t*)(l + i * 1024), 16, 0, 0);
}

__device__ __forceinline__ int pack_bf16(float a, float b) {
    const unsigned short ua = __builtin_bit_cast(unsigned short, (__bf16)a);
    const unsigned short ub = __builtin_bit_cast(unsigned short, (__bf16)b);
    return (int)((unsigned)ua | ((unsigned)ub << 16));
}

__global__ __launch_bounds__(512, 2)
void fa_main(const float* __restrict__ Qg, const __bf16* __restrict__ kimg,
             const __bf16* __restrict__ vimg, float* __restrict__ Og) {
    // Full double buffering: one barrier per iteration, DMAs get a whole
    // iteration of flight time before the vmcnt(0)+barrier drain.
    __shared__ __bf16 Kbuf[2][64 * 256];   // 2 x 32 KB swizzled K image
    __shared__ __bf16 Vbuf[2][256 * 64];   // 2 x 32 KB swizzled V^T image

    const int tid  = threadIdx.x;
    const int wave = tid >> 6;             // 0..7
    const int lane = tid & 63;
    const int n16  = lane & 15;
    const int quad = lane >> 4;
    const int n167 = n16 & 7;

    const int linear = blockIdx.x;         // 0..511
    const int bh = ((linear & 7) << 2) + (linear >> 7);  // XCD-grouped bh
    const int qt = (linear >> 3) & 15;

    const size_t base = (size_t)bh * (S_LEN * D_DIM);
    const char* ktile = (const char*)(kimg + ((size_t)bh << 19));
    const char* vtile = (const char*)(vimg + ((size_t)bh << 19));
    const int woff = wave * 4096 + lane * 16;   // per-lane DMA source offset
    const int ldso = wave * 4096;               // wave-uniform LDS dest offset

    // ---- Q fragments (B operand: B[k=quad*8+j][n=query n16]) ----
    short8 qfrag[8];
    {
        const float* qrow = Qg + base + (size_t)(qt * BM + wave * 16 + n16) * D_DIM;
        #pragma unroll
        for (int kk = 0; kk < 8; ++kk) {
            const float4v a = *(const float4v*)(qrow + kk * 32 + quad * 8);
            const float4v b = *(const float4v*)(qrow + kk * 32 + quad * 8 + 4);
            short8 f;
            f[0] = __builtin_bit_cast(short, (__bf16)(a[0] * QSCALE));
            f[1] = __builtin_bit_cast(short, (__bf16)(a[1] * QSCALE));
            f[2] = __builtin_bit_cast(short, (__bf16)(a[2] * QSCALE));
            f[3] = __builtin_bit_cast(short, (__bf16)(a[3] * QSCALE));
            f[4] = __builtin_bit_cast(short, (__bf16)(b[0] * QSCALE));
            f[5] = __builtin_bit_cast(short, (__bf16)(b[1] * QSCALE));
            f[6] = __builtin_bit_cast(short, (__bf16)(b[2] * QSCALE));
            f[7] = __builtin_bit_cast(short, (__bf16)(b[3] * QSCALE));
            qfrag[kk] = f;
        }
    }

    float4v oacc[16];
    #pragma unroll
    for (int i = 0; i < 16; ++i) oacc[i] = (float4v){0.f, 0.f, 0.f, 0.f};
    float m_run = NEG_BIG, l_run = 0.f;   // per-lane softmax state of query n16

    // prime tile 0
    dma4(ktile + woff, (char*)&Kbuf[0][0] + ldso);
    dma4(vtile + woff, (char*)&Vbuf[0][0] + ldso);

    const int srcA = n16 + ((lane & 16) << 1);   // (n16, quad'=2*(q&1))
    const int srcB = srcA + 16;                  // (n16, quad'=2*(q&1)+1)
    const bool hi  = (quad >> 1) != 0;

    for (int kt = 0; kt < NKT; ++kt) {
        const int p = kt & 1;
        __syncthreads();   // drains K(kt),V(kt) DMAs (one full iter in flight);
                           // orders all reads of buf[1-p] before its refill
        if (kt + 1 < NKT) {
            dma4(ktile + (kt + 1) * 32768 + woff, (char*)&Kbuf[1 - p][0] + ldso);
            dma4(vtile + (kt + 1) * 32768 + woff, (char*)&Vbuf[1 - p][0] + ldso);
        }

        // ---- S^T = K * Q^T : lane holds keys {16nt+4quad+r}, query n16 ----
        float4v sacc[4];
        #pragma unroll
        for (int nt = 0; nt < 4; ++nt) {
            float4v acc = {0.f, 0.f, 0.f, 0.f};
            const __bf16* kp = &Kbuf[p][(nt * 16 + n16) * 256];
            #pragma unroll
            for (int kk = 0; kk < 8; ++kk) {
                const short8 kfrag = *(const short8*)(kp + (((4 * kk + quad) ^ n167) << 3));
                acc = __builtin_amdgcn_mfma_f32_16x16x32_bf16(kfrag, qfrag[kk], acc, 0, 0, 0);
            }
            sacc[nt] = acc;
        }

        // ---- online softmax: lane-local over 16 keys, cross-quad over 64 ----
        float mx = sacc[0][0];
        #pragma unroll
        for (int nt = 0; nt < 4; ++nt)
            #pragma unroll
            for (int r = 0; r < 4; ++r) mx = fmaxf(mx, sacc[nt][r]);
        mx = fmaxf(mx, __shfl_xor(mx, 16));
        mx = fmaxf(mx, __shfl_xor(mx, 32));
        const float mn = fmaxf(m_run, mx);
        const float al = exp2f(m_run - mn);
        m_run = mn;

        float ps = 0.f;
        int pk[4][2];
        #pragma unroll
        for (int nt = 0; nt < 4; ++nt) {
            float p0 = exp2f(sacc[nt][0] - mn);
            float p1 = exp2f(sacc[nt][1] - mn);
            float p2 = exp2f(sacc[nt][2] - mn);
            float p3 = exp2f(sacc[nt][3] - mn);
            ps += (p0 + p1) + (p2 + p3);
            pk[nt][0] = pack_bf16(p0, p1);
            pk[nt][1] = pack_bf16(p2, p3);
        }
        ps += __shfl_xor(ps, 16);
        ps += __shfl_xor(ps, 32);
        l_run = l_run * al + ps;

        // rescale O only when some query's max changed (rare after warmup)
        if (__ballot(al != 1.0f)) {
            #pragma unroll
            for (int r = 0; r < 4; ++r) {
                const float alr = __shfl(al, 20 * quad + r);  // lane(n16=4q+r, quad'=q)
                #pragma unroll
                for (int dt = 0; dt < 16; ++dt) oacc[dt][r] *= alr;
            }
        }

        // ---- P: C-layout -> A-frags via cross-quad shuffles ----
        short8 pfrag[2];
        #pragma unroll
        for (int kth = 0; kth < 2; ++kth) {
            const int a0 = __shfl(pk[2 * kth][0], srcA), a1 = __shfl(pk[2 * kth + 1][0], srcA);
            const int b0 = __shfl(pk[2 * kth][1], srcA), b1 = __shfl(pk[2 * kth + 1][1], srcA);
            const int c0 = __shfl(pk[2 * kth][0], srcB), c1 = __shfl(pk[2 * kth + 1][0], srcB);
            const int d0 = __shfl(pk[2 * kth][1], srcB), d1 = __shfl(pk[2 * kth + 1][1], srcB);
            uint4v u;
            u[0] = (unsigned)(hi ? a1 : a0);
            u[1] = (unsigned)(hi ? b1 : b0);
            u[2] = (unsigned)(hi ? c1 : c0);
            u[3] = (unsigned)(hi ? d1 : d0);
            pfrag[kth] = __builtin_bit_cast(short8, u);
        }

        // ---- O += P V  (B-frags from swizzled V^T image) ----
        #pragma unroll
        for (int kth = 0; kth < 2; ++kth) {
            #pragma unroll
            for (int dt = 0; dt < 16; ++dt) {
                const short8 vfrag = *(const short8*)
                    &Vbuf[p][(dt * 16 + n16) * 64 + (((4 * kth + quad) ^ n167) << 3)];
                oacc[dt] = __builtin_amdgcn_mfma_f32_16x16x32_bf16(pfrag[kth], vfrag, oacc[dt], 0, 0, 0);
            }
        }
    }

    // ---- epilogue ----
    float* obase = Og + base + (size_t)(qt * BM + wave * 16) * D_DIM;
    #pragma unroll
    for (int r = 0; r < 4; ++r) {
        const float lr  = __shfl(l_run, 20 * quad + r);
        const float inv = 1.0f / lr;
        const int row = (quad << 2) + r;
        #pragma unroll
        for (int dt = 0; dt < 16; ++dt)
            obase[row * D_DIM + dt * 16 + n16] = oacc[dt][r] * inv;
    }
}

// ---------------- fallback (round-1 kernel, used when ws too small) -------------
__global__ __launch_bounds__(256, 3)
void fa_fallback(const float* __restrict__ Qg, const float* __restrict__ Kg,
                 const float* __restrict__ Vg, float* __restrict__ Og)
{
    __shared__ __bf16 kv[256 * 72];
    __shared__ __bf16 pbuf[4 * 16 * 72];
    const int tid = threadIdx.x, wave = tid >> 6, lane = tid & 63;
    const int n16 = lane & 15, quad = lane >> 4;
    const int linear = blockIdx.x;
    const int bh = ((linear & 7) << 2) + (linear >> 8);
    const int qt = (linear >> 3) & 31;
    const size_t base = (size_t)bh * S_LEN * D_DIM;
    short8 qfrag[8];
    {
        const float* qrow = Qg + base + (size_t)(qt * 64 + wave * 16 + n16) * D_DIM;
        #pragma unroll
        for (int kk = 0; kk < 8; ++kk) {
            const float4v a = *(const float4v*)(qrow + kk * 32 + quad * 8);
            const float4v b = *(const float4v*)(qrow + kk * 32 + quad * 8 + 4);
            short8 f;
            f[0] = __builtin_bit_cast(short, (__bf16)(a[0] * QSCALE));
            f[1] = __builtin_bit_cast(short, (__bf16)(a[1] * QSCALE));
            f[2] = __builtin_bit_cast(short, (__bf16)(a[2] * QSCALE));
            f[3] = __builtin_bit_cast(short, (__bf16)(a[3] * QSCALE));
            f[4] = __builtin_bit_cast(short, (__bf16)(b[0] * QSCALE));
            f[5] = __builtin_bit_cast(short, (__bf16)(b[1] * QSCALE));
            f[6] = __builtin_bit_cast(short, (__bf16)(b[2] * QSCALE));
            f[7] = __builtin_bit_cast(short, (__bf16)(b[3] * QSCALE));
            qfrag[kk] = f;
        }
    }
    float4v oacc[16];
    #pragma unroll
    for (int i = 0; i < 16; ++i) oacc[i] = (float4v){0.f, 0.f, 0.f, 0.f};
    float m_run[4] = {NEG_BIG, NEG_BIG, NEG_BIG, NEG_BIG};
    float l_run[4] = {0.f, 0.f, 0.f, 0.f};
    for (int kt = 0; kt < S_LEN / BN; ++kt) {
        {
            const float* kbase = Kg + base + (size_t)kt * BN * D_DIM;
            #pragma unroll 4
            for (int it = 0; it < 16; ++it) {
                const int g = it * 256 + tid;
                const int row = g >> 6;
                const int dc = (g & 63) << 2;
                const float4v v = *(const float4v*)(kbase + row * D_DIM + dc);
                bf16x4 w;
                w[0] = (__bf16)v[0]; w[1] = (__bf16)v[1];
                w[2] = (__bf16)v[2]; w[3] = (__bf16)v[3];
                *(bf16x4*)&kv[row * 264 + dc] = w;
            }
        }
        __syncthreads();
        float4v sacc[4];
        #pragma unroll
        for (int nt = 0; nt < 4; ++nt) {
            float4v acc = {0.f, 0.f, 0.f, 0.f};
            const __bf16* kp = &kv[(nt * 16 + n16) * 264 + quad * 8];
            #pragma unroll
            for (int kk = 0; kk < 8; ++kk) {
                const short8 bfr = *(const short8*)(kp + kk * 32);
                acc = __builtin_amdgcn_mfma_f32_16x16x32_bf16(qfrag[kk], bfr, acc, 0, 0, 0);
            }
            sacc[nt] = acc;
        }
        __syncthreads();
        {
            const float* vbase = Vg + base + (size_t)kt * BN * D_DIM;
            #pragma unroll 4
            for (int it = 0; it < 8; ++it) {
                const int tsk = it * 256 + tid;
                const int kp2 = tsk >> 6;
                const int dc = (tsk & 63) << 2;
                const float4v v0 = *(const float4v*)(vbase + (2 * kp2) * D_DIM + dc);
                const float4v v1 = *(const float4v*)(vbase + (2 * kp2 + 1) * D_DIM + dc);
                #pragma unroll
                for (int i = 0; i < 4; ++i) {
                    bf16x2 w; w[0] = (__bf16)v0[i]; w[1] = (__bf16)v1[i];
                    *(bf16x2*)&kv[(dc + i) * 72 + 2 * kp2] = w;
                }
            }
        }
        #pragma unroll
        for (int r = 0; r < 4; ++r) {
            float mx = fmaxf(fmaxf(sacc[0][r], sacc[1][r]), fmaxf(sacc[2][r], sacc[3][r]));
            mx = fmaxf(mx, __shfl_xor(mx, 1));
            mx = fmaxf(mx, __shfl_xor(mx, 2));
            mx = fmaxf(mx, __shfl_xor(mx, 4));
            mx = fmaxf(mx, __shfl_xor(mx, 8));
            const float mn = fmaxf(m_run[r], mx);
            const float al = exp2f(m_run[r] - mn);
            m_run[r] = mn;
            float ps = 0.f;
            __bf16* prow = &pbuf[wave * 1152 + (quad * 4 + r) * 72 + n16];
            #pragma unroll
            for (int nt = 0; nt < 4; ++nt) {
                const float p = exp2f(sacc[nt][r] - mn);
                ps += p;
                prow[nt * 16] = (__bf16)p;
            }
            ps += __shfl_xor(ps, 1);
            ps += __shfl_xor(ps, 2);
            ps += __shfl_xor(ps, 4);
            ps += __shfl_xor(ps, 8);
            l_run[r] = l_run[r] * al + ps;
            #pragma unroll
            for (int dt = 0; dt < 16; ++dt) oacc[dt][r] *= al;
        }
        __syncthreads();
        #pragma unroll
        for (int kth = 0; kth < 2; ++kth) {
            const short8 af = *(const short8*)&pbuf[wave * 1152 + n16 * 72 + kth * 32 + quad * 8];
            #pragma unroll
            for (int dt = 0; dt < 16; ++dt) {
                const short8 bfr = *(const short8*)&kv[(dt * 16 + n16) * 72 + kth * 32 + quad * 8];
                oacc[dt] = __builtin_amdgcn_mfma_f32_16x16x32_bf16(af, bfr, oacc[dt], 0, 0, 0);
            }
        }
        __syncthreads();
    }
    float* obase = Og + base + (size_t)(qt * 64 + wave * 16) * D_DIM;
    #pragma unroll
    for (int r = 0; r < 4; ++r) {
        const float inv = 1.0f / l_run[r];
        const int row = quad * 4 + r;
        #pragma unroll
        for (int dt = 0; dt < 16; ++dt)
            obase[row * D_DIM + dt * 16 + n16] = oacc[dt][r] * inv;
    }
}

extern "C" void kernel_launch(void* const* d_in, const int* in_sizes, int n_in,
                              void* d_out, int out_size, void* d_ws, size_t ws_size,
                              hipStream_t stream) {
    const float* Q = (const float*)d_in[0];
    const float* K = (const float*)d_in[1];
    const float* V = (const float*)d_in[2];
    float* O = (float*)d_out;
    (void)in_sizes; (void)n_in; (void)out_size;
    if (ws_size >= WS_NEED) {
        __bf16* kimg = (__bf16*)d_ws;
        __bf16* vimg = kimg + (size_t)NBH * NKT * TILE_ELS;
        prep_k<<<dim3(8192), dim3(256), 0, stream>>>(K, kimg);
        prep_v<<<dim3(1024), dim3(256), 0, stream>>>(V, vimg);
        fa_main<<<dim3(512), dim3(512), 0, stream>>>(Q, kimg, vimg, O);
    } else {
        fa_fallback<<<dim3(1024), dim3(256), 0, stream>>>(Q, K, V, O);
    }
}